// Round 12
// baseline (292.255 us; speedup 1.0000x reference)
//
#include <hip/hip_runtime.h>

#define D 128
#define NG 64

#define SCAN_CHUNK 16
#define SCAN_BLOCK 256
#define SCAN_TILE (SCAN_CHUNK * SCAN_BLOCK)  // 4096

#define FILL_CHUNKS 125   // E=800K -> chunk 6400, 16B-aligned int4 groups

typedef unsigned short ushort_t;
typedef unsigned int uint_t;
typedef __attribute__((ext_vector_type(8))) short short8;
typedef __attribute__((ext_vector_type(4))) float f32x4;
typedef __attribute__((ext_vector_type(4))) int i32x4;   // clang vector: builtin-compatible

__device__ __forceinline__ float bflo(uint_t w) { return __uint_as_float(w << 16); }
__device__ __forceinline__ float bfhi(uint_t w) { return __uint_as_float(w & 0xFFFF0000u); }
__device__ __forceinline__ float bf2f(ushort_t u) { return __uint_as_float(((uint_t)u) << 16); }
__device__ __forceinline__ ushort_t f2bf(float f) {
  uint_t x = __float_as_uint(f);
  x = x + 0x7FFFu + ((x >> 16) & 1u);
  return (ushort_t)(x >> 16);
}

// ---- converted-parameter element offsets (f32 scratch) ----
static constexpr int OW1 = 0, OB1 = 16384, OW2 = 16512, OB2 = 32896, OW3 = 33024,
                     OB3 = 49408, OFW1 = 49536, OFB1 = 57728, OFW2 = 57792,
                     OFB2 = 59840, OFW3 = 59872, OFB3 = 59904, WTOT = 59905;
static constexpr int WT_ELEMS = 3 * 16384;

// ------- fused params kernel: per-block dtype detect + convert + W-transpose -------
__global__ __launch_bounds__(256) void params_kernel(
    const ushort_t* __restrict__ x,
    const void* W1, const void* b1, const void* W2, const void* b2,
    const void* W3, const void* b3, const void* fw1, const void* fb1,
    const void* fw2, const void* fb2, const void* fw3, const void* fb3,
    int* __restrict__ flag, float* __restrict__ wconv, ushort_t* __restrict__ wt) {
  __shared__ int bad;
  if (threadIdx.x == 0) bad = 0;
  __syncthreads();
  int b = 0;
  for (int i = threadIdx.x; i < 4096; i += 256) {
    ushort_t u = x[i];
    int e = (u >> 7) & 0xFF;
    if (e == 0xFF || fabsf(bf2f(u)) > 1e6f) b++;
  }
  if (b) atomicAdd(&bad, b);
  __syncthreads();
  const bool bf = (bad == 0);
  if (blockIdx.x == 0 && threadIdx.x == 0) *flag = bf ? 1 : 0;

  int i = blockIdx.x * 256 + threadIdx.x;
  if (i < WTOT) {
    const void* src; int local;
    if      (i < OB1)  { src = W1;  local = i; }
    else if (i < OW2)  { src = b1;  local = i - OB1; }
    else if (i < OB2)  { src = W2;  local = i - OW2; }
    else if (i < OW3)  { src = b2;  local = i - OB2; }
    else if (i < OB3)  { src = W3;  local = i - OW3; }
    else if (i < OFW1) { src = b3;  local = i - OB3; }
    else if (i < OFB1) { src = fw1; local = i - OFW1; }
    else if (i < OFW2) { src = fb1; local = i - OFB1; }
    else if (i < OFB2) { src = fw2; local = i - OFW2; }
    else if (i < OFW3) { src = fb2; local = i - OFB2; }
    else if (i < OFB3) { src = fw3; local = i - OFW3; }
    else               { src = fb3; local = i - OFB3; }
    wconv[i] = bf ? bf2f(((const ushort_t*)src)[local]) : ((const float*)src)[local];
  } else if (i < WTOT + WT_ELEMS) {
    int j = i - WTOT;
    int L = j >> 14, rem = j & 16383;
    int nIdx = rem >> 7, k = rem & 127;
    const void* src = (L == 0) ? W1 : (L == 1) ? W2 : W3;
    int idx = k * D + nIdx;
    float v = bf ? bf2f(((const ushort_t*)src)[idx]) : ((const float*)src)[idx];
    wt[j] = f2bf(v);   // wt[L][n][k] = W_L[k][n]
  }
}

// ---------------- CSR build, XCD-local octiles + nontemporal int4 edge stream ----------------
__global__ __launch_bounds__(256) void deg_kernel(const int* __restrict__ ei,
                                                  int* __restrict__ deg, int E, int octSize) {
  const int oct = blockIdx.x & 7;
  int chunkSz = ((E + FILL_CHUNKS - 1) / FILL_CHUNKS + 3) & ~3;
  const int c0 = (blockIdx.x >> 3) * chunkSz;
  const int c1 = min(c0 + chunkSz, E);
  const int lo = oct * octSize, hi = lo + octSize;
  if ((E & 3) == 0) {
    const int ng = (c1 - c0) >> 2;
    for (int g = threadIdx.x; g < ng; g += 256) {
      i32x4 d = __builtin_nontemporal_load(
          reinterpret_cast<const i32x4*>(&ei[E + c0 + g * 4]));
      if (d.x >= lo && d.x < hi) atomicAdd(&deg[d.x], 1);
      if (d.y >= lo && d.y < hi) atomicAdd(&deg[d.y], 1);
      if (d.z >= lo && d.z < hi) atomicAdd(&deg[d.z], 1);
      if (d.w >= lo && d.w < hi) atomicAdd(&deg[d.w], 1);
    }
  } else {
    for (int i = c0 + threadIdx.x; i < c1; i += 256) {
      int dst = __builtin_nontemporal_load(&ei[E + i]);
      if (dst >= lo && dst < hi) atomicAdd(&deg[dst], 1);
    }
  }
}

// ---------------- scan phase1: block sums + dinv fused ----------------
__global__ __launch_bounds__(SCAN_BLOCK) void scan_phase1(const int* __restrict__ deg,
                                                          float* __restrict__ dinv,
                                                          int* __restrict__ blockSum, int n) {
  __shared__ int sh[SCAN_BLOCK];
  const int t = threadIdx.x;
  const int base = blockIdx.x * SCAN_TILE + t * SCAN_CHUNK;
  int s = 0;
  #pragma unroll
  for (int i = 0; i < SCAN_CHUNK; i++) {
    int idx = base + i;
    if (idx < n) {
      int dg = deg[idx];
      s += dg;
      dinv[idx] = rsqrtf((float)(dg + 1));  // +1 self loop
    }
  }
  sh[t] = s;
  __syncthreads();
  for (int off = SCAN_BLOCK / 2; off > 0; off >>= 1) {
    if (t < off) sh[t] += sh[t + off];
    __syncthreads();
  }
  if (t == 0) blockSum[blockIdx.x] = sh[0];
}

// ---------------- scan phase3: per-block scan, prefix of blockSums computed inline ----------------
__global__ __launch_bounds__(SCAN_BLOCK) void scan_phase3(const int* __restrict__ deg,
                                                          const int* __restrict__ blockSum,
                                                          int* __restrict__ row,
                                                          int* __restrict__ cur, int n, int nb) {
  __shared__ int sh[SCAN_BLOCK];
  const int t = threadIdx.x;
  const int base = blockIdx.x * SCAN_TILE + t * SCAN_CHUNK;
  int pre = 0;
  for (int bm = 0; bm < (int)blockIdx.x; bm++) pre += blockSum[bm];  // nb<=13, trivial
  int v[SCAN_CHUNK];
  int s = 0;
  #pragma unroll
  for (int i = 0; i < SCAN_CHUNK; i++) {
    int idx = base + i;
    v[i] = (idx < n) ? deg[idx] : 0;
    s += v[i];
  }
  sh[t] = s;
  __syncthreads();
  for (int off = 1; off < SCAN_BLOCK; off <<= 1) {
    int val = (t >= off) ? sh[t - off] : 0;
    __syncthreads();
    sh[t] += val;
    __syncthreads();
  }
  int excl = ((t == 0) ? 0 : sh[t - 1]) + pre;
  #pragma unroll
  for (int i = 0; i < SCAN_CHUNK; i++) {
    int idx = base + i;
    if (idx < n) { row[idx] = excl; cur[idx] = excl; excl += v[i]; }
  }
  if ((int)blockIdx.x == nb - 1 && t == SCAN_BLOCK - 1) row[n] = pre + sh[SCAN_BLOCK - 1];
}

__global__ __launch_bounds__(256) void fill_kernel(const int* __restrict__ ei,
                                                   int* __restrict__ cur,
                                                   int* __restrict__ csr, int E, int octSize) {
  const int oct = blockIdx.x & 7;
  int chunkSz = ((E + FILL_CHUNKS - 1) / FILL_CHUNKS + 3) & ~3;
  const int c0 = (blockIdx.x >> 3) * chunkSz;
  const int c1 = min(c0 + chunkSz, E);
  const int lo = oct * octSize, hi = lo + octSize;
  if ((E & 3) == 0) {
    const int ng = (c1 - c0) >> 2;
    for (int g = threadIdx.x; g < ng; g += 256) {
      const int base = c0 + g * 4;
      i32x4 d = __builtin_nontemporal_load(reinterpret_cast<const i32x4*>(&ei[E + base]));
      bool h0 = d.x >= lo && d.x < hi, h1 = d.y >= lo && d.y < hi;
      bool h2 = d.z >= lo && d.z < hi, h3 = d.w >= lo && d.w < hi;
      if (h0 | h1 | h2 | h3) {
        i32x4 sv = __builtin_nontemporal_load(reinterpret_cast<const i32x4*>(&ei[base]));
        if (h0) csr[atomicAdd(&cur[d.x], 1)] = sv.x;
        if (h1) csr[atomicAdd(&cur[d.y], 1)] = sv.y;
        if (h2) csr[atomicAdd(&cur[d.z], 1)] = sv.z;
        if (h3) csr[atomicAdd(&cur[d.w], 1)] = sv.w;
      }
    }
  } else {
    for (int i = c0 + threadIdx.x; i < c1; i += 256) {
      int dst = __builtin_nontemporal_load(&ei[E + i]);
      if (dst >= lo && dst < hi) {
        int src = __builtin_nontemporal_load(&ei[i]);
        csr[atomicAdd(&cur[dst], 1)] = src;
      }
    }
  }
}

// ------- MFMA GEMM, BM=128: out[n][128](bf16) = (A[n][128] @ W) * dinv[r] -------
// 128 rows/block halves per-block W-stage cost vs BM=64. 4 waves x 2 M-tiles
// x 8 N-tiles, 16x16x32 bf16 MFMA; W in LDS with XOR swizzle; LDS-transpose
// epilogue (reusing W buffer) keeps uint4 stores.
__global__ __launch_bounds__(256) void gemm128_mfma(const void* __restrict__ Ain,
                                                    const ushort_t* __restrict__ Wt,
                                                    const float* __restrict__ dinv,
                                                    ushort_t* __restrict__ out, int n,
                                                    const int* __restrict__ flag,
                                                    int src_is_input) {
  __shared__ ushort_t wlds[128 * 128];  // 32 KB
  const int tid = threadIdx.x;

  {  // stage W, swizzled: 2048 uint4 chunks; dst_chunk = c ^ ((c>>4)&7)
    const uint4* srcp = (const uint4*)Wt;
    uint4* dstp = (uint4*)wlds;
    #pragma unroll
    for (int i = 0; i < 8; i++) {
      int c = tid + i * 256;
      dstp[c ^ ((c >> 4) & 7)] = srcp[c];
    }
  }
  __syncthreads();

  const int w = tid >> 6, lane = tid & 63;
  const int lrow = lane & 15, lk = lane >> 4;
  const int rbase = blockIdx.x * 128 + w * 32;
  const bool bf = src_is_input ? (*flag != 0) : true;

  f32x4 acc[2][8];
  #pragma unroll
  for (int m = 0; m < 2; m++)
    #pragma unroll
    for (int t = 0; t < 8; t++) acc[m][t] = (f32x4){0.f, 0.f, 0.f, 0.f};

  #pragma unroll
  for (int ks = 0; ks < 4; ks++) {
    short8 af[2];
    #pragma unroll
    for (int m = 0; m < 2; m++) {
      int node = rbase + m * 16 + lrow;
      if (node < n) {
        if (bf) {
          af[m] = *reinterpret_cast<const short8*>(
              (const ushort_t*)Ain + (size_t)node * D + ks * 32 + lk * 8);
        } else {
          const float* Af = (const float*)Ain + (size_t)node * D + ks * 32 + lk * 8;
          float4 a0 = *reinterpret_cast<const float4*>(Af);
          float4 a1 = *reinterpret_cast<const float4*>(Af + 4);
          af[m] = (short8){(short)f2bf(a0.x), (short)f2bf(a0.y), (short)f2bf(a0.z), (short)f2bf(a0.w),
                           (short)f2bf(a1.x), (short)f2bf(a1.y), (short)f2bf(a1.z), (short)f2bf(a1.w)};
        }
      } else {
        af[m] = (short8){0, 0, 0, 0, 0, 0, 0, 0};
      }
    }
    #pragma unroll
    for (int t = 0; t < 8; t++) {
      int chunk = (t * 16 + lrow) * 16 + ks * 4 + lk;
      int swz = chunk ^ (lrow & 7);
      short8 bfrag = *reinterpret_cast<const short8*>((const uint4*)wlds + swz);
      acc[0][t] = __builtin_amdgcn_mfma_f32_16x16x32_bf16(af[0], bfrag, acc[0][t], 0, 0, 0);
      acc[1][t] = __builtin_amdgcn_mfma_f32_16x16x32_bf16(af[1], bfrag, acc[1][t], 0, 0, 0);
    }
  }

  __syncthreads();  // all waves done reading W; reuse LDS for epilogue staging

  #pragma unroll
  for (int m = 0; m < 2; m++) {
    float dv[4];
    #pragma unroll
    for (int j = 0; j < 4; j++) {
      int r = rbase + m * 16 + lk * 4 + j;
      dv[j] = (r < n) ? dinv[r] : 0.f;
    }
    ushort_t* st = wlds + (w * 32 + m * 16) * D;
    #pragma unroll
    for (int t = 0; t < 8; t++) {
      #pragma unroll
      for (int j = 0; j < 4; j++) {
        int rr = lk * 4 + j;
        int idx = rr * D + t * 16 + lrow;
        st[idx ^ ((rr & 7) << 3)] = f2bf(acc[m][t][j] * dv[j]);
      }
    }
  }
  __syncthreads();

  const int rloc = lane >> 1;          // 0..31 within wave stripe
  const int ms = rloc >> 4, rr = rloc & 15;
  const ushort_t* st = wlds + (w * 32 + ms * 16) * D;
  const int r = rbase + rloc;
  if (r < n) {
    #pragma unroll
    for (int it = 0; it < 8; it++) {
      int col = (lane & 1) * 8 + it * 16;
      uint4 v = *reinterpret_cast<const uint4*>(&st[rr * D + (col ^ ((rr & 7) << 3))]);
      *reinterpret_cast<uint4*>(&out[(size_t)r * D + col]) = v;
    }
  }
}

// ------- aggregation: h' pre-scaled by dinv[src]. out[i] = di*(h'[i] + Σ h'[src]) + b -------
// Grid-stride waves; one 64-lane wave per node; unroll-8 gather chains.
// csr/row streams loaded nontemporal: keep the 4MiB/XCD L2 for the randomly
// gathered 12.8MB h rows, not the sequential index stream.
__global__ __launch_bounds__(256) void aggregate(const ushort_t* __restrict__ h,
                                                 const int* __restrict__ row,
                                                 const int* __restrict__ csr,
                                                 const float* __restrict__ dinv,
                                                 const float* __restrict__ bias,
                                                 ushort_t* __restrict__ out, int n, int do_elu) {
  const int wid = (blockIdx.x * 256 + threadIdx.x) >> 6;
  const int nw = (gridDim.x * 256) >> 6;
  const int lane = threadIdx.x & 63;
  float2 bv = *reinterpret_cast<const float2*>(&bias[lane * 2]);
  for (int gid = wid; gid < n; gid += nw) {
    uint_t hv = *reinterpret_cast<const uint_t*>(&h[(size_t)gid * D + lane * 2]);
    float ax = bflo(hv), ay = bfhi(hv);
    const int s = __builtin_nontemporal_load(&row[gid]);
    const int e = __builtin_nontemporal_load(&row[gid + 1]);
    int idx = s;
    for (; idx + 7 < e; idx += 8) {
      int s0 = __builtin_nontemporal_load(&csr[idx]);
      int s1 = __builtin_nontemporal_load(&csr[idx + 1]);
      int s2 = __builtin_nontemporal_load(&csr[idx + 2]);
      int s3 = __builtin_nontemporal_load(&csr[idx + 3]);
      int s4 = __builtin_nontemporal_load(&csr[idx + 4]);
      int s5 = __builtin_nontemporal_load(&csr[idx + 5]);
      int s6 = __builtin_nontemporal_load(&csr[idx + 6]);
      int s7 = __builtin_nontemporal_load(&csr[idx + 7]);
      uint_t m0 = *reinterpret_cast<const uint_t*>(&h[(size_t)s0 * D + lane * 2]);
      uint_t m1 = *reinterpret_cast<const uint_t*>(&h[(size_t)s1 * D + lane * 2]);
      uint_t m2 = *reinterpret_cast<const uint_t*>(&h[(size_t)s2 * D + lane * 2]);
      uint_t m3 = *reinterpret_cast<const uint_t*>(&h[(size_t)s3 * D + lane * 2]);
      uint_t m4 = *reinterpret_cast<const uint_t*>(&h[(size_t)s4 * D + lane * 2]);
      uint_t m5 = *reinterpret_cast<const uint_t*>(&h[(size_t)s5 * D + lane * 2]);
      uint_t m6 = *reinterpret_cast<const uint_t*>(&h[(size_t)s6 * D + lane * 2]);
      uint_t m7 = *reinterpret_cast<const uint_t*>(&h[(size_t)s7 * D + lane * 2]);
      ax += bflo(m0); ay += bfhi(m0);
      ax += bflo(m1); ay += bfhi(m1);
      ax += bflo(m2); ay += bfhi(m2);
      ax += bflo(m3); ay += bfhi(m3);
      ax += bflo(m4); ay += bfhi(m4);
      ax += bflo(m5); ay += bfhi(m5);
      ax += bflo(m6); ay += bfhi(m6);
      ax += bflo(m7); ay += bfhi(m7);
    }
    for (; idx + 3 < e; idx += 4) {
      int s0 = __builtin_nontemporal_load(&csr[idx]);
      int s1 = __builtin_nontemporal_load(&csr[idx + 1]);
      int s2 = __builtin_nontemporal_load(&csr[idx + 2]);
      int s3 = __builtin_nontemporal_load(&csr[idx + 3]);
      uint_t m0 = *reinterpret_cast<const uint_t*>(&h[(size_t)s0 * D + lane * 2]);
      uint_t m1 = *reinterpret_cast<const uint_t*>(&h[(size_t)s1 * D + lane * 2]);
      uint_t m2 = *reinterpret_cast<const uint_t*>(&h[(size_t)s2 * D + lane * 2]);
      uint_t m3 = *reinterpret_cast<const uint_t*>(&h[(size_t)s3 * D + lane * 2]);
      ax += bflo(m0); ay += bfhi(m0);
      ax += bflo(m1); ay += bfhi(m1);
      ax += bflo(m2); ay += bfhi(m2);
      ax += bflo(m3); ay += bfhi(m3);
    }
    for (; idx < e; idx++) {
      int s0 = __builtin_nontemporal_load(&csr[idx]);
      uint_t m0 = *reinterpret_cast<const uint_t*>(&h[(size_t)s0 * D + lane * 2]);
      ax += bflo(m0); ay += bfhi(m0);
    }
    const float di = dinv[gid];
    float ox = ax * di + bv.x;
    float oy = ay * di + bv.y;
    if (do_elu) {
      ox = ox > 0.f ? ox : expm1f(ox);
      oy = oy > 0.f ? oy : expm1f(oy);
    }
    uint_t o = (uint_t)f2bf(ox) | ((uint_t)f2bf(oy) << 16);
    *reinterpret_cast<uint_t*>(&out[(size_t)gid * D + lane * 2]) = o;
  }
}

// ------- pooling (+ per-graph counts fused into block 0): batch sorted, run-length flush -------
__global__ __launch_bounds__(256) void pool_kernel(const ushort_t* __restrict__ h,
                                                   const int* __restrict__ batch,
                                                   float* __restrict__ pooled,
                                                   float* __restrict__ cnt, int n) {
  if (blockIdx.x == 0 && threadIdx.x < NG) {
    int g = threadIdx.x;
    int lo = 0, hi = n;
    while (lo < hi) { int mid = (lo + hi) >> 1; if (batch[mid] < g) lo = mid + 1; else hi = mid; }
    int a = lo;
    lo = 0; hi = n;
    while (lo < hi) { int mid = (lo + hi) >> 1; if (batch[mid] < g + 1) lo = mid + 1; else hi = mid; }
    cnt[g] = (float)(lo - a);
  }
  const int c  = threadIdx.x & 63;
  const int rl = threadIdx.x >> 6;
  const int base = blockIdx.x * 64;
  if (base >= n) return;
  const int end = min(base + 64, n);
  float sx = 0.f, sy = 0.f;
  int curg = -1;
  for (int i = base + rl; i < end; i += 4) {
    int g = batch[i];
    if (g != curg) {
      if (curg >= 0) {
        unsafeAtomicAdd(&pooled[curg * D + 2 * c], sx);
        unsafeAtomicAdd(&pooled[curg * D + 2 * c + 1], sy);
      }
      curg = g; sx = 0.f; sy = 0.f;
    }
    uint_t v = *reinterpret_cast<const uint_t*>(&h[(size_t)i * D + 2 * c]);
    sx += bflo(v); sy += bfhi(v);
  }
  if (curg >= 0) {
    unsafeAtomicAdd(&pooled[curg * D + 2 * c], sx);
    unsafeAtomicAdd(&pooled[curg * D + 2 * c + 1], sy);
  }
}

// ---------------- MLP head: one block per graph (f32 weights, f32 output) ----------------
__global__ __launch_bounds__(64) void mlp_kernel(const float* __restrict__ pooled,
                                                 const float* __restrict__ cnt,
                                                 const float* __restrict__ wf,
                                                 float* __restrict__ out) {
  __shared__ float g[128], h1[64], h2[32];
  const int gi = blockIdx.x, t = threadIdx.x;
  float c = fmaxf(cnt[gi], 1.0f);
  g[t] = pooled[gi * D + t] / c;
  g[t + 64] = pooled[gi * D + 64 + t] / c;
  __syncthreads();
  float a = wf[OFB1 + t];
  for (int k = 0; k < 128; k++) a += g[k] * wf[OFW1 + k * 64 + t];
  h1[t] = fmaxf(a, 0.f);
  __syncthreads();
  if (t < 32) {
    float a2 = wf[OFB2 + t];
    for (int k = 0; k < 64; k++) a2 += h1[k] * wf[OFW2 + k * 32 + t];
    h2[t] = fmaxf(a2, 0.f);
  }
  __syncthreads();
  if (t == 0) {
    float a3 = wf[OFB3];
    for (int k = 0; k < 32; k++) a3 += h2[k] * wf[OFW3 + k];
    out[gi] = a3;
  }
}

extern "C" void kernel_launch(void* const* d_in, const int* in_sizes, int n_in,
                              void* d_out, int out_size, void* d_ws, size_t ws_size,
                              hipStream_t stream) {
  (void)n_in; (void)out_size; (void)ws_size;
  const int* ei    = (const int*)d_in[13];
  const int* batch = (const int*)d_in[14];
  const int N = in_sizes[14];
  const int E = in_sizes[13] / 2;
  const int octSize = (N + 7) / 8;

  char* ws = (char*)d_ws;
  size_t off = 0;
  auto take = [&](size_t bytes) -> char* {
    char* p = ws + off;
    off += (bytes + 255) & ~(size_t)255;
    return p;
  };
  int*     flag   = (int*)take(4);
  int*     deg    = (int*)take((size_t)N * 4);
  float*   dinv   = (float*)take((size_t)N * 4);
  int*     row    = (int*)take((size_t)(N + 1) * 4);
  int*     cur    = (int*)take((size_t)N * 4);
  int*     csr    = (int*)take((size_t)E * 4);
  float*   wconv  = (float*)take((size_t)WTOT * 4);
  ushort_t* wt    = (ushort_t*)take((size_t)WT_ELEMS * 2);
  int*     bsum   = (int*)take(1024 * 4);
  ushort_t* bufA  = (ushort_t*)take((size_t)N * D * 2);
  ushort_t* bufB  = (ushort_t*)take((size_t)N * D * 2);
  float*   pooled = (float*)take((size_t)NG * D * 4);
  float*   cnt    = (float*)take((size_t)NG * 4);

  hipMemsetAsync(deg, 0, (size_t)N * 4, stream);
  hipMemsetAsync(pooled, 0, (size_t)NG * D * 4, stream);

  const int pgrid = (WTOT + WT_ELEMS + 255) / 256;
  params_kernel<<<pgrid, 256, 0, stream>>>(
      (const ushort_t*)d_in[0], d_in[1], d_in[2], d_in[3], d_in[4], d_in[5], d_in[6],
      d_in[7], d_in[8], d_in[9], d_in[10], d_in[11], d_in[12], flag, wconv, wt);

  deg_kernel<<<FILL_CHUNKS * 8, 256, 0, stream>>>(ei, deg, E, octSize);

  const int nbScan = (N + SCAN_TILE - 1) / SCAN_TILE;
  scan_phase1<<<nbScan, SCAN_BLOCK, 0, stream>>>(deg, dinv, bsum, N);
  scan_phase3<<<nbScan, SCAN_BLOCK, 0, stream>>>(deg, bsum, row, cur, N, nbScan);

  fill_kernel<<<FILL_CHUNKS * 8, 256, 0, stream>>>(ei, cur, csr, E, octSize);

  const int gemm_grid = (N + 127) / 128;
  const int agg_grid = 2048;

  gemm128_mfma<<<gemm_grid, 256, 0, stream>>>(d_in[0], wt, dinv, bufA, N, flag, 1);
  aggregate<<<agg_grid, 256, 0, stream>>>(bufA, row, csr, dinv, wconv + OB1, bufB, N, 1);
  gemm128_mfma<<<gemm_grid, 256, 0, stream>>>((const void*)bufB, wt + 16384, dinv, bufA, N, flag, 0);
  aggregate<<<agg_grid, 256, 0, stream>>>(bufA, row, csr, dinv, wconv + OB2, bufB, N, 1);
  gemm128_mfma<<<gemm_grid, 256, 0, stream>>>((const void*)bufB, wt + 32768, dinv, bufA, N, flag, 0);
  aggregate<<<agg_grid, 256, 0, stream>>>(bufA, row, csr, dinv, wconv + OB3, bufB, N, 0);

  pool_kernel<<<(N + 63) / 64, 256, 0, stream>>>(bufB, batch, pooled, cnt, N);
  mlp_kernel<<<NG, 64, 0, stream>>>(pooled, cnt, wconv, (float*)d_out);
}

// Round 13
// 266.977 us; speedup vs baseline: 1.0947x; 1.0947x over previous
//
#include <hip/hip_runtime.h>

#define D 128
#define NG 64

#define SCAN_CHUNK 16
#define SCAN_BLOCK 256
#define SCAN_TILE (SCAN_CHUNK * SCAN_BLOCK)  // 4096

#define FILL_CHUNKS 125   // E=800K -> chunk 6400, 16B-aligned int4 groups

typedef unsigned short ushort_t;
typedef unsigned int uint_t;
typedef __attribute__((ext_vector_type(8))) short short8;
typedef __attribute__((ext_vector_type(4))) float f32x4;
typedef __attribute__((ext_vector_type(4))) int i32x4;   // clang vector: builtin-compatible

__device__ __forceinline__ float bflo(uint_t w) { return __uint_as_float(w << 16); }
__device__ __forceinline__ float bfhi(uint_t w) { return __uint_as_float(w & 0xFFFF0000u); }
__device__ __forceinline__ float bf2f(ushort_t u) { return __uint_as_float(((uint_t)u) << 16); }
__device__ __forceinline__ ushort_t f2bf(float f) {
  uint_t x = __float_as_uint(f);
  x = x + 0x7FFFu + ((x >> 16) & 1u);
  return (ushort_t)(x >> 16);
}

// ---- converted-parameter element offsets (f32 scratch) ----
static constexpr int OW1 = 0, OB1 = 16384, OW2 = 16512, OB2 = 32896, OW3 = 33024,
                     OB3 = 49408, OFW1 = 49536, OFB1 = 57728, OFW2 = 57792,
                     OFB2 = 59840, OFW3 = 59872, OFB3 = 59904, WTOT = 59905;
static constexpr int WT_ELEMS = 3 * 16384;

// ROUND-12 LESSONS (both reverted here):
//  - NT csr/row loads in aggregate: FETCH 82->88MB, +2 us/dispatch. NT evicts
//    the sequential index stream between batches; h-gather L2 pressure was not
//    the binding constraint. Keep PLAIN loads.
//  - GEMM BM=128: grid 391 blocks -> poor CU balance at 1 block/CU (32KB LDS),
//    worse epilogue coalescing. Keep BM=64 (782 blocks).

// ------- fused params kernel: per-block dtype detect + convert + W-transpose -------
__global__ __launch_bounds__(256) void params_kernel(
    const ushort_t* __restrict__ x,
    const void* W1, const void* b1, const void* W2, const void* b2,
    const void* W3, const void* b3, const void* fw1, const void* fb1,
    const void* fw2, const void* fb2, const void* fw3, const void* fb3,
    int* __restrict__ flag, float* __restrict__ wconv, ushort_t* __restrict__ wt) {
  __shared__ int bad;
  if (threadIdx.x == 0) bad = 0;
  __syncthreads();
  int b = 0;
  for (int i = threadIdx.x; i < 4096; i += 256) {
    ushort_t u = x[i];
    int e = (u >> 7) & 0xFF;
    if (e == 0xFF || fabsf(bf2f(u)) > 1e6f) b++;
  }
  if (b) atomicAdd(&bad, b);
  __syncthreads();
  const bool bf = (bad == 0);
  if (blockIdx.x == 0 && threadIdx.x == 0) *flag = bf ? 1 : 0;

  int i = blockIdx.x * 256 + threadIdx.x;
  if (i < WTOT) {
    const void* src; int local;
    if      (i < OB1)  { src = W1;  local = i; }
    else if (i < OW2)  { src = b1;  local = i - OB1; }
    else if (i < OB2)  { src = W2;  local = i - OW2; }
    else if (i < OW3)  { src = b2;  local = i - OB2; }
    else if (i < OB3)  { src = W3;  local = i - OW3; }
    else if (i < OFW1) { src = b3;  local = i - OB3; }
    else if (i < OFB1) { src = fw1; local = i - OFW1; }
    else if (i < OFW2) { src = fb1; local = i - OFB1; }
    else if (i < OFB2) { src = fw2; local = i - OFW2; }
    else if (i < OFW3) { src = fb2; local = i - OFB2; }
    else if (i < OFB3) { src = fw3; local = i - OFW3; }
    else               { src = fb3; local = i - OFB3; }
    wconv[i] = bf ? bf2f(((const ushort_t*)src)[local]) : ((const float*)src)[local];
  } else if (i < WTOT + WT_ELEMS) {
    int j = i - WTOT;
    int L = j >> 14, rem = j & 16383;
    int nIdx = rem >> 7, k = rem & 127;
    const void* src = (L == 0) ? W1 : (L == 1) ? W2 : W3;
    int idx = k * D + nIdx;
    float v = bf ? bf2f(((const ushort_t*)src)[idx]) : ((const float*)src)[idx];
    wt[j] = f2bf(v);   // wt[L][n][k] = W_L[k][n]
  }
}

// ---------------- CSR build, XCD-local octiles + nontemporal int4 edge stream ----------------
__global__ __launch_bounds__(256) void deg_kernel(const int* __restrict__ ei,
                                                  int* __restrict__ deg, int E, int octSize) {
  const int oct = blockIdx.x & 7;
  int chunkSz = ((E + FILL_CHUNKS - 1) / FILL_CHUNKS + 3) & ~3;
  const int c0 = (blockIdx.x >> 3) * chunkSz;
  const int c1 = min(c0 + chunkSz, E);
  const int lo = oct * octSize, hi = lo + octSize;
  if ((E & 3) == 0) {
    const int ng = (c1 - c0) >> 2;
    for (int g = threadIdx.x; g < ng; g += 256) {
      i32x4 d = __builtin_nontemporal_load(
          reinterpret_cast<const i32x4*>(&ei[E + c0 + g * 4]));
      if (d.x >= lo && d.x < hi) atomicAdd(&deg[d.x], 1);
      if (d.y >= lo && d.y < hi) atomicAdd(&deg[d.y], 1);
      if (d.z >= lo && d.z < hi) atomicAdd(&deg[d.z], 1);
      if (d.w >= lo && d.w < hi) atomicAdd(&deg[d.w], 1);
    }
  } else {
    for (int i = c0 + threadIdx.x; i < c1; i += 256) {
      int dst = __builtin_nontemporal_load(&ei[E + i]);
      if (dst >= lo && dst < hi) atomicAdd(&deg[dst], 1);
    }
  }
}

// ---------------- scan phase1: block sums + dinv fused ----------------
__global__ __launch_bounds__(SCAN_BLOCK) void scan_phase1(const int* __restrict__ deg,
                                                          float* __restrict__ dinv,
                                                          int* __restrict__ blockSum, int n) {
  __shared__ int sh[SCAN_BLOCK];
  const int t = threadIdx.x;
  const int base = blockIdx.x * SCAN_TILE + t * SCAN_CHUNK;
  int s = 0;
  #pragma unroll
  for (int i = 0; i < SCAN_CHUNK; i++) {
    int idx = base + i;
    if (idx < n) {
      int dg = deg[idx];
      s += dg;
      dinv[idx] = rsqrtf((float)(dg + 1));  // +1 self loop
    }
  }
  sh[t] = s;
  __syncthreads();
  for (int off = SCAN_BLOCK / 2; off > 0; off >>= 1) {
    if (t < off) sh[t] += sh[t + off];
    __syncthreads();
  }
  if (t == 0) blockSum[blockIdx.x] = sh[0];
}

// ---------------- scan phase3: per-block scan, prefix of blockSums computed inline ----------------
__global__ __launch_bounds__(SCAN_BLOCK) void scan_phase3(const int* __restrict__ deg,
                                                          const int* __restrict__ blockSum,
                                                          int* __restrict__ row,
                                                          int* __restrict__ cur, int n, int nb) {
  __shared__ int sh[SCAN_BLOCK];
  const int t = threadIdx.x;
  const int base = blockIdx.x * SCAN_TILE + t * SCAN_CHUNK;
  int pre = 0;
  for (int bm = 0; bm < (int)blockIdx.x; bm++) pre += blockSum[bm];  // nb<=13, trivial
  int v[SCAN_CHUNK];
  int s = 0;
  #pragma unroll
  for (int i = 0; i < SCAN_CHUNK; i++) {
    int idx = base + i;
    v[i] = (idx < n) ? deg[idx] : 0;
    s += v[i];
  }
  sh[t] = s;
  __syncthreads();
  for (int off = 1; off < SCAN_BLOCK; off <<= 1) {
    int val = (t >= off) ? sh[t - off] : 0;
    __syncthreads();
    sh[t] += val;
    __syncthreads();
  }
  int excl = ((t == 0) ? 0 : sh[t - 1]) + pre;
  #pragma unroll
  for (int i = 0; i < SCAN_CHUNK; i++) {
    int idx = base + i;
    if (idx < n) { row[idx] = excl; cur[idx] = excl; excl += v[i]; }
  }
  if ((int)blockIdx.x == nb - 1 && t == SCAN_BLOCK - 1) row[n] = pre + sh[SCAN_BLOCK - 1];
}

__global__ __launch_bounds__(256) void fill_kernel(const int* __restrict__ ei,
                                                   int* __restrict__ cur,
                                                   int* __restrict__ csr, int E, int octSize) {
  const int oct = blockIdx.x & 7;
  int chunkSz = ((E + FILL_CHUNKS - 1) / FILL_CHUNKS + 3) & ~3;
  const int c0 = (blockIdx.x >> 3) * chunkSz;
  const int c1 = min(c0 + chunkSz, E);
  const int lo = oct * octSize, hi = lo + octSize;
  if ((E & 3) == 0) {
    const int ng = (c1 - c0) >> 2;
    for (int g = threadIdx.x; g < ng; g += 256) {
      const int base = c0 + g * 4;
      i32x4 d = __builtin_nontemporal_load(reinterpret_cast<const i32x4*>(&ei[E + base]));
      bool h0 = d.x >= lo && d.x < hi, h1 = d.y >= lo && d.y < hi;
      bool h2 = d.z >= lo && d.z < hi, h3 = d.w >= lo && d.w < hi;
      if (h0 | h1 | h2 | h3) {
        i32x4 sv = __builtin_nontemporal_load(reinterpret_cast<const i32x4*>(&ei[base]));
        if (h0) csr[atomicAdd(&cur[d.x], 1)] = sv.x;
        if (h1) csr[atomicAdd(&cur[d.y], 1)] = sv.y;
        if (h2) csr[atomicAdd(&cur[d.z], 1)] = sv.z;
        if (h3) csr[atomicAdd(&cur[d.w], 1)] = sv.w;
      }
    }
  } else {
    for (int i = c0 + threadIdx.x; i < c1; i += 256) {
      int dst = __builtin_nontemporal_load(&ei[E + i]);
      if (dst >= lo && dst < hi) {
        int src = __builtin_nontemporal_load(&ei[i]);
        csr[atomicAdd(&cur[dst], 1)] = src;
      }
    }
  }
}

// ------- MFMA GEMM, BM=64: out[n][128](bf16) = (A[n][128] @ W) * dinv[r] -------
__global__ __launch_bounds__(256) void gemm128_mfma(const void* __restrict__ Ain,
                                                    const ushort_t* __restrict__ Wt,
                                                    const float* __restrict__ dinv,
                                                    ushort_t* __restrict__ out, int n,
                                                    const int* __restrict__ flag,
                                                    int src_is_input) {
  __shared__ ushort_t wlds[128 * 128];  // 32 KB
  const int tid = threadIdx.x;

  {  // stage W, swizzled: 2048 uint4 chunks; dst_chunk = c ^ ((c>>4)&7)
    const uint4* srcp = (const uint4*)Wt;
    uint4* dstp = (uint4*)wlds;
    #pragma unroll
    for (int i = 0; i < 8; i++) {
      int c = tid + i * 256;
      dstp[c ^ ((c >> 4) & 7)] = srcp[c];
    }
  }
  __syncthreads();

  const int w = tid >> 6, lane = tid & 63;
  const int lrow = lane & 15, lk = lane >> 4;
  const int r0 = blockIdx.x * 64 + w * 16;
  const int node = r0 + lrow;
  const bool bf = src_is_input ? (*flag != 0) : true;

  f32x4 acc[8];
  #pragma unroll
  for (int t = 0; t < 8; t++) acc[t] = (f32x4){0.f, 0.f, 0.f, 0.f};

  #pragma unroll
  for (int ks = 0; ks < 4; ks++) {
    short8 af;
    if (node < n) {
      if (bf) {
        af = *reinterpret_cast<const short8*>(
            (const ushort_t*)Ain + (size_t)node * D + ks * 32 + lk * 8);
      } else {
        const float* Af = (const float*)Ain + (size_t)node * D + ks * 32 + lk * 8;
        float4 a0 = *reinterpret_cast<const float4*>(Af);
        float4 a1 = *reinterpret_cast<const float4*>(Af + 4);
        af = (short8){(short)f2bf(a0.x), (short)f2bf(a0.y), (short)f2bf(a0.z), (short)f2bf(a0.w),
                      (short)f2bf(a1.x), (short)f2bf(a1.y), (short)f2bf(a1.z), (short)f2bf(a1.w)};
      }
    } else {
      af = (short8){0, 0, 0, 0, 0, 0, 0, 0};
    }
    #pragma unroll
    for (int t = 0; t < 8; t++) {
      int chunk = (t * 16 + lrow) * 16 + ks * 4 + lk;
      int swz = chunk ^ (lrow & 7);
      short8 bfrag = *reinterpret_cast<const short8*>((const uint4*)wlds + swz);
      acc[t] = __builtin_amdgcn_mfma_f32_16x16x32_bf16(af, bfrag, acc[t], 0, 0, 0);
    }
  }

  __syncthreads();  // all waves done reading W; reuse LDS for epilogue staging

  float dv[4];
  #pragma unroll
  for (int j = 0; j < 4; j++) {
    int r = r0 + lk * 4 + j;
    dv[j] = (r < n) ? dinv[r] : 0.f;
  }
  ushort_t* st = wlds + w * 16 * D;
  #pragma unroll
  for (int t = 0; t < 8; t++) {
    #pragma unroll
    for (int j = 0; j < 4; j++) {
      int rr = lk * 4 + j;
      int idx = rr * D + t * 16 + lrow;
      st[idx ^ ((rr & 7) << 3)] = f2bf(acc[t][j] * dv[j]);
    }
  }
  __syncthreads();

  const int rrow = lane >> 2;
  const int cbase = (lane & 3) * 8;
  #pragma unroll
  for (int it = 0; it < 4; it++) {
    int col = cbase + it * 32;
    int idx = rrow * D + col;
    uint4 v = *reinterpret_cast<const uint4*>(&st[idx ^ ((rrow & 7) << 3)]);
    if (r0 + rrow < n)
      *reinterpret_cast<uint4*>(&out[(size_t)(r0 + rrow) * D + col]) = v;
  }
}

// ------- aggregation: h' pre-scaled by dinv[src]. out[i] = di*(h'[i] + Σ h'[src]) + b -------
// Grid-stride waves; one 64-lane wave per node; unroll-8 gather chains; PLAIN loads.
__global__ __launch_bounds__(256) void aggregate(const ushort_t* __restrict__ h,
                                                 const int* __restrict__ row,
                                                 const int* __restrict__ csr,
                                                 const float* __restrict__ dinv,
                                                 const float* __restrict__ bias,
                                                 ushort_t* __restrict__ out, int n, int do_elu) {
  const int wid = (blockIdx.x * 256 + threadIdx.x) >> 6;
  const int nw = (gridDim.x * 256) >> 6;
  const int lane = threadIdx.x & 63;
  float2 bv = *reinterpret_cast<const float2*>(&bias[lane * 2]);
  for (int gid = wid; gid < n; gid += nw) {
    uint_t hv = *reinterpret_cast<const uint_t*>(&h[(size_t)gid * D + lane * 2]);
    float ax = bflo(hv), ay = bfhi(hv);
    const int s = row[gid], e = row[gid + 1];
    int idx = s;
    for (; idx + 7 < e; idx += 8) {
      int s0 = csr[idx],     s1 = csr[idx + 1], s2 = csr[idx + 2], s3 = csr[idx + 3];
      int s4 = csr[idx + 4], s5 = csr[idx + 5], s6 = csr[idx + 6], s7 = csr[idx + 7];
      uint_t m0 = *reinterpret_cast<const uint_t*>(&h[(size_t)s0 * D + lane * 2]);
      uint_t m1 = *reinterpret_cast<const uint_t*>(&h[(size_t)s1 * D + lane * 2]);
      uint_t m2 = *reinterpret_cast<const uint_t*>(&h[(size_t)s2 * D + lane * 2]);
      uint_t m3 = *reinterpret_cast<const uint_t*>(&h[(size_t)s3 * D + lane * 2]);
      uint_t m4 = *reinterpret_cast<const uint_t*>(&h[(size_t)s4 * D + lane * 2]);
      uint_t m5 = *reinterpret_cast<const uint_t*>(&h[(size_t)s5 * D + lane * 2]);
      uint_t m6 = *reinterpret_cast<const uint_t*>(&h[(size_t)s6 * D + lane * 2]);
      uint_t m7 = *reinterpret_cast<const uint_t*>(&h[(size_t)s7 * D + lane * 2]);
      ax += bflo(m0); ay += bfhi(m0);
      ax += bflo(m1); ay += bfhi(m1);
      ax += bflo(m2); ay += bfhi(m2);
      ax += bflo(m3); ay += bfhi(m3);
      ax += bflo(m4); ay += bfhi(m4);
      ax += bflo(m5); ay += bfhi(m5);
      ax += bflo(m6); ay += bfhi(m6);
      ax += bflo(m7); ay += bfhi(m7);
    }
    for (; idx + 3 < e; idx += 4) {
      int s0 = csr[idx], s1 = csr[idx + 1], s2 = csr[idx + 2], s3 = csr[idx + 3];
      uint_t m0 = *reinterpret_cast<const uint_t*>(&h[(size_t)s0 * D + lane * 2]);
      uint_t m1 = *reinterpret_cast<const uint_t*>(&h[(size_t)s1 * D + lane * 2]);
      uint_t m2 = *reinterpret_cast<const uint_t*>(&h[(size_t)s2 * D + lane * 2]);
      uint_t m3 = *reinterpret_cast<const uint_t*>(&h[(size_t)s3 * D + lane * 2]);
      ax += bflo(m0); ay += bfhi(m0);
      ax += bflo(m1); ay += bfhi(m1);
      ax += bflo(m2); ay += bfhi(m2);
      ax += bflo(m3); ay += bfhi(m3);
    }
    for (; idx < e; idx++) {
      int s0 = csr[idx];
      uint_t m0 = *reinterpret_cast<const uint_t*>(&h[(size_t)s0 * D + lane * 2]);
      ax += bflo(m0); ay += bfhi(m0);
    }
    const float di = dinv[gid];
    float ox = ax * di + bv.x;
    float oy = ay * di + bv.y;
    if (do_elu) {
      ox = ox > 0.f ? ox : expm1f(ox);
      oy = oy > 0.f ? oy : expm1f(oy);
    }
    uint_t o = (uint_t)f2bf(ox) | ((uint_t)f2bf(oy) << 16);
    *reinterpret_cast<uint_t*>(&out[(size_t)gid * D + lane * 2]) = o;
  }
}

// ------- pooling (+ per-graph counts fused into block 0): batch sorted, run-length flush -------
__global__ __launch_bounds__(256) void pool_kernel(const ushort_t* __restrict__ h,
                                                   const int* __restrict__ batch,
                                                   float* __restrict__ pooled,
                                                   float* __restrict__ cnt, int n) {
  if (blockIdx.x == 0 && threadIdx.x < NG) {
    int g = threadIdx.x;
    int lo = 0, hi = n;
    while (lo < hi) { int mid = (lo + hi) >> 1; if (batch[mid] < g) lo = mid + 1; else hi = mid; }
    int a = lo;
    lo = 0; hi = n;
    while (lo < hi) { int mid = (lo + hi) >> 1; if (batch[mid] < g + 1) lo = mid + 1; else hi = mid; }
    cnt[g] = (float)(lo - a);
  }
  const int c  = threadIdx.x & 63;
  const int rl = threadIdx.x >> 6;
  const int base = blockIdx.x * 64;
  if (base >= n) return;
  const int end = min(base + 64, n);
  float sx = 0.f, sy = 0.f;
  int curg = -1;
  for (int i = base + rl; i < end; i += 4) {
    int g = batch[i];
    if (g != curg) {
      if (curg >= 0) {
        unsafeAtomicAdd(&pooled[curg * D + 2 * c], sx);
        unsafeAtomicAdd(&pooled[curg * D + 2 * c + 1], sy);
      }
      curg = g; sx = 0.f; sy = 0.f;
    }
    uint_t v = *reinterpret_cast<const uint_t*>(&h[(size_t)i * D + 2 * c]);
    sx += bflo(v); sy += bfhi(v);
  }
  if (curg >= 0) {
    unsafeAtomicAdd(&pooled[curg * D + 2 * c], sx);
    unsafeAtomicAdd(&pooled[curg * D + 2 * c + 1], sy);
  }
}

// ---------------- MLP head: one block per graph (f32 weights, f32 output) ----------------
__global__ __launch_bounds__(64) void mlp_kernel(const float* __restrict__ pooled,
                                                 const float* __restrict__ cnt,
                                                 const float* __restrict__ wf,
                                                 float* __restrict__ out) {
  __shared__ float g[128], h1[64], h2[32];
  const int gi = blockIdx.x, t = threadIdx.x;
  float c = fmaxf(cnt[gi], 1.0f);
  g[t] = pooled[gi * D + t] / c;
  g[t + 64] = pooled[gi * D + 64 + t] / c;
  __syncthreads();
  float a = wf[OFB1 + t];
  for (int k = 0; k < 128; k++) a += g[k] * wf[OFW1 + k * 64 + t];
  h1[t] = fmaxf(a, 0.f);
  __syncthreads();
  if (t < 32) {
    float a2 = wf[OFB2 + t];
    for (int k = 0; k < 64; k++) a2 += h1[k] * wf[OFW2 + k * 32 + t];
    h2[t] = fmaxf(a2, 0.f);
  }
  __syncthreads();
  if (t == 0) {
    float a3 = wf[OFB3];
    for (int k = 0; k < 32; k++) a3 += h2[k] * wf[OFW3 + k];
    out[gi] = a3;
  }
}

extern "C" void kernel_launch(void* const* d_in, const int* in_sizes, int n_in,
                              void* d_out, int out_size, void* d_ws, size_t ws_size,
                              hipStream_t stream) {
  (void)n_in; (void)out_size; (void)ws_size;
  const int* ei    = (const int*)d_in[13];
  const int* batch = (const int*)d_in[14];
  const int N = in_sizes[14];
  const int E = in_sizes[13] / 2;
  const int octSize = (N + 7) / 8;

  char* ws = (char*)d_ws;
  size_t off = 0;
  auto take = [&](size_t bytes) -> char* {
    char* p = ws + off;
    off += (bytes + 255) & ~(size_t)255;
    return p;
  };
  int*     flag   = (int*)take(4);
  int*     deg    = (int*)take((size_t)N * 4);
  float*   dinv   = (float*)take((size_t)N * 4);
  int*     row    = (int*)take((size_t)(N + 1) * 4);
  int*     cur    = (int*)take((size_t)N * 4);
  int*     csr    = (int*)take((size_t)E * 4);
  float*   wconv  = (float*)take((size_t)WTOT * 4);
  ushort_t* wt    = (ushort_t*)take((size_t)WT_ELEMS * 2);
  int*     bsum   = (int*)take(1024 * 4);
  ushort_t* bufA  = (ushort_t*)take((size_t)N * D * 2);
  ushort_t* bufB  = (ushort_t*)take((size_t)N * D * 2);
  float*   pooled = (float*)take((size_t)NG * D * 4);
  float*   cnt    = (float*)take((size_t)NG * 4);

  hipMemsetAsync(deg, 0, (size_t)N * 4, stream);
  hipMemsetAsync(pooled, 0, (size_t)NG * D * 4, stream);

  const int pgrid = (WTOT + WT_ELEMS + 255) / 256;
  params_kernel<<<pgrid, 256, 0, stream>>>(
      (const ushort_t*)d_in[0], d_in[1], d_in[2], d_in[3], d_in[4], d_in[5], d_in[6],
      d_in[7], d_in[8], d_in[9], d_in[10], d_in[11], d_in[12], flag, wconv, wt);

  deg_kernel<<<FILL_CHUNKS * 8, 256, 0, stream>>>(ei, deg, E, octSize);

  const int nbScan = (N + SCAN_TILE - 1) / SCAN_TILE;
  scan_phase1<<<nbScan, SCAN_BLOCK, 0, stream>>>(deg, dinv, bsum, N);
  scan_phase3<<<nbScan, SCAN_BLOCK, 0, stream>>>(deg, bsum, row, cur, N, nbScan);

  fill_kernel<<<FILL_CHUNKS * 8, 256, 0, stream>>>(ei, cur, csr, E, octSize);

  const int gemm_grid = (N + 63) / 64;
  const int agg_grid = 2048;

  gemm128_mfma<<<gemm_grid, 256, 0, stream>>>(d_in[0], wt, dinv, bufA, N, flag, 1);
  aggregate<<<agg_grid, 256, 0, stream>>>(bufA, row, csr, dinv, wconv + OB1, bufB, N, 1);
  gemm128_mfma<<<gemm_grid, 256, 0, stream>>>((const void*)bufB, wt + 16384, dinv, bufA, N, flag, 0);
  aggregate<<<agg_grid, 256, 0, stream>>>(bufA, row, csr, dinv, wconv + OB2, bufB, N, 1);
  gemm128_mfma<<<gemm_grid, 256, 0, stream>>>((const void*)bufB, wt + 32768, dinv, bufA, N, flag, 0);
  aggregate<<<agg_grid, 256, 0, stream>>>(bufA, row, csr, dinv, wconv + OB3, bufB, N, 0);

  pool_kernel<<<(N + 63) / 64, 256, 0, stream>>>(bufB, batch, pooled, cnt, N);
  mlp_kernel<<<NG, 64, 0, stream>>>(pooled, cnt, wconv, (float*)d_out);
}